// Round 2
// 406.010 us; speedup vs baseline: 1.0986x; 1.0986x over previous
//
#include <hip/hip_runtime.h>

#define NN 131072   // total nodes (256 graphs x 512)
#define NE 1048576  // edges
// ws layout (bytes); total used = 0x3300000 (< 0x4200000 available)
#define OFF_DEG_OUT 0x000000   // int[NN]
#define OFF_CURSOR  0x080000   // int[NN] -> becomes deg_in
#define OFF_WT      0x100000   // bf16 3x[128][128] transposed layer weights (96 KB)
#define OFF_WTI     0x118000   // bf16 [128][96] transposed init weight, K-padded (24 KB)
#define OFF_BUCKET  0x200000   // int[NN][64] adjacency buckets (33.5 MB)
#define OFF_HN      0x2200000  // int8[NN][128] ping buffer A (16.8 MB)
#define OFF_SCA     0x3200000  // float[NN] per-row dequant scale for buffer A
#define OFF_SCB     0x3280000  // float[NN] per-row dequant scale for buffer B

typedef __attribute__((ext_vector_type(8))) short bf16x8;
typedef __attribute__((ext_vector_type(4))) float f32x4;

static __device__ __forceinline__ float blo(unsigned u){ return __uint_as_float(u << 16); }
static __device__ __forceinline__ float bhi(unsigned u){ return __uint_as_float(u & 0xffff0000u); }
static __device__ __forceinline__ unsigned f2b(float f){
    unsigned u = __float_as_uint(f);
    return (u + 0x7fffu + ((u >> 16) & 1u)) >> 16;   // round-to-nearest-even
}
static __device__ __forceinline__ unsigned pack2(float a, float b){
    return f2b(a) | (f2b(b) << 16);
}
static __device__ __forceinline__ unsigned packq(int q0, int q1, int q2, int q3){
    return (q0 & 255) | ((q1 & 255) << 8) | ((q2 & 255) << 16) | ((q3 & 255) << 24);
}

// deg_out count + bucketed CSR build; 2 edges/thread (2M far-atomics = structural floor)
__global__ __launch_bounds__(256) void k_fill(const int* __restrict__ src,
                                              const int* __restrict__ dst,
                                              int* __restrict__ deg_out,
                                              int* __restrict__ cursor,
                                              int* __restrict__ bucket) {
    int base = (blockIdx.x * 256 + threadIdx.x) * 2;
    int2 s2 = *(const int2*)&src[base];
    int2 d2 = *(const int2*)&dst[base];
    int p0 = atomicAdd(&cursor[d2.x], 1);
    int p1 = atomicAdd(&cursor[d2.y], 1);
    atomicAdd(&deg_out[s2.x], 1);
    atomicAdd(&deg_out[s2.y], 1);
    if (p0 < 64) bucket[(size_t)d2.x * 64 + p0] = s2.x;   // deg>=64 has P~1e-40
    if (p1 < 64) bucket[(size_t)d2.y * 64 + p1] = s2.y;
}

// weight transposes + zero deg/cursor (replaces the hipMemsetAsync dispatch).
// grid = 256 blocks = 65536 threads; each zeroes one uint4 of the 1 MB counter region.
__global__ __launch_bounds__(256) void k_wprep(const float* __restrict__ W1,
                                               const float* __restrict__ W2,
                                               const float* __restrict__ W3,
                                               const float* __restrict__ Wi,
                                               unsigned short* __restrict__ Wt,
                                               unsigned short* __restrict__ Wti,
                                               uint4* __restrict__ zdst) {
    int idx = blockIdx.x * 256 + threadIdx.x;
    zdst[idx] = (uint4){0u, 0u, 0u, 0u};
    if (idx < 49152) {
        int L = idx >> 14, rem = idx & 16383;
        int k = rem >> 7, n = rem & 127;
        const float* W = L == 0 ? W1 : (L == 1 ? W2 : W3);
        Wt[L * 16384 + n * 128 + k] = (unsigned short)f2b(W[k * 128 + n]);
    } else if (idx < 61440) {
        int rem = idx - 49152;
        int n = rem / 96, k = rem - n * 96;
        float v = (k < 74) ? Wi[k * 128 + n] : 0.f;
        Wti[n * 96 + k] = (unsigned short)f2b(v);
    }
}

// hn0 = int8_rowscaled((x @ W_init) * deg_out^-1/2) via MFMA; X staged+quantized in LDS.
// hn0 is pre-ReLU (signed): q = rint(v * 127/amax), dequant scale = amax/127.
__global__ __launch_bounds__(256) void k_init(const float* __restrict__ X,
                                              const unsigned short* __restrict__ Wti,
                                              const int* __restrict__ deg_out,
                                              unsigned char* __restrict__ hn,
                                              float* __restrict__ scInv) {
    __shared__ unsigned int xs[64 * 68];   // 17.4 KB; staging + epilogue reuse
    int tid = threadIdx.x;
    int m0 = blockIdx.x * 64;

    for (int idx = tid; idx < 2368; idx += 256) {        // X: 64 rows x 37 float2, quantize
        int m = idx / 37, t = idx - m * 37;
        float2 v = *(const float2*)&X[(size_t)(m0 + m) * 74 + t * 2];
        xs[m * 68 + t] = pack2(v.x, v.y);
    }
    for (int idx = tid; idx < 64 * 11; idx += 256) {     // zero pad words 37..47 (K 74..95)
        int m = idx / 11, c = 37 + idx % 11;
        xs[m * 68 + c] = 0u;
    }
    __syncthreads();

    int wave = tid >> 6, lane = tid & 63, quad = lane >> 4, l16 = lane & 15;
    f32x4 acc[8];
    #pragma unroll
    for (int t = 0; t < 8; ++t) acc[t] = (f32x4){0.f, 0.f, 0.f, 0.f};
    int arow = (wave * 16 + l16) * 68 + quad * 4;
    #pragma unroll
    for (int ks = 0; ks < 3; ++ks) {
        bf16x8 af = *(const bf16x8*)&xs[arow + ks * 16];
        #pragma unroll
        for (int t = 0; t < 8; ++t) {
            bf16x8 bf = *(const bf16x8*)(Wti + (t * 16 + l16) * 96 + ks * 32 + quad * 8);
            acc[t] = __builtin_amdgcn_mfma_f32_16x16x32_bf16(af, bf, acc[t], 0, 0, 0);
        }
    }
    __syncthreads();   // done reading xs; reuse as bf16 epilogue tile [64][136 shorts]
    unsigned short* atb = (unsigned short*)xs;
    int mb = wave * 16 + quad * 4;
    float nsr[4];
    #pragma unroll
    for (int r = 0; r < 4; ++r) {
        int dq = deg_out[m0 + mb + r];
        nsr[r] = rsqrtf((float)(dq > 1 ? dq : 1));
    }
    #pragma unroll
    for (int t = 0; t < 8; ++t)
        #pragma unroll
        for (int r = 0; r < 4; ++r)
            atb[(mb + r) * 136 + t * 16 + l16] = (unsigned short)f2b(acc[t][r] * nsr[r]);
    __syncthreads();
    {   // int8 write-out: 4 threads own a row; row-amax via shfl_xor; 32 B/thread coalesced
        int r = tid >> 2, cg = tid & 3;
        const unsigned int* sp = &xs[r * 68 + cg * 16];   // 16 words = 32 bf16 values
        float v[32]; float am = 0.f;
        #pragma unroll
        for (int j = 0; j < 16; ++j) {
            unsigned u = sp[j];
            float e = blo(u), o = bhi(u);
            v[2 * j] = e; v[2 * j + 1] = o;
            am = fmaxf(am, fmaxf(fabsf(e), fabsf(o)));
        }
        am = fmaxf(am, __shfl_xor(am, 1));
        am = fmaxf(am, __shfl_xor(am, 2));
        float scl = am > 1e-30f ? 127.f / am : 0.f;
        if (cg == 0) scInv[m0 + r] = am * (1.f / 127.f);
        unsigned w[8];
        #pragma unroll
        for (int j = 0; j < 8; ++j)
            w[j] = packq((int)rintf(v[4 * j] * scl),     (int)rintf(v[4 * j + 1] * scl),
                         (int)rintf(v[4 * j + 2] * scl), (int)rintf(v[4 * j + 3] * scl));
        uint4* op = (uint4*)(hn + (size_t)(m0 + r) * 128 + cg * 32);
        op[0] = (uint4){w[0], w[1], w[2], w[3]};
        op[1] = (uint4){w[4], w[5], w[6], w[7]};
    }
}

// dequant 8 bytes (one neighbor slice): signed int8 (hn0) — compiler emits bfe+cvt
#define DEQS8(vv, ss) do {                                                     \
    unsigned ux = (vv).x, uy = (vv).y;                                         \
    a0 = fmaf((ss), (float)(int)(signed char)(ux),       a0);                  \
    a1 = fmaf((ss), (float)(int)(signed char)(ux >> 8),  a1);                  \
    a2 = fmaf((ss), (float)(int)(signed char)(ux >> 16), a2);                  \
    a3 = fmaf((ss), (float)(int)(signed char)(ux >> 24), a3);                  \
    a4 = fmaf((ss), (float)(int)(signed char)(uy),       a4);                  \
    a5 = fmaf((ss), (float)(int)(signed char)(uy >> 8),  a5);                  \
    a6 = fmaf((ss), (float)(int)(signed char)(uy >> 16), a6);                  \
    a7 = fmaf((ss), (float)(int)(signed char)(uy >> 24), a7);                  \
} while (0)

// unsigned uint8 (post-ReLU hn1/hn2) — compiler emits v_cvt_f32_ubyte0..3
#define DEQU8(vv, ss) do {                                                     \
    unsigned ux = (vv).x, uy = (vv).y;                                         \
    a0 = fmaf((ss), (float)(ux & 255),         a0);                            \
    a1 = fmaf((ss), (float)((ux >> 8) & 255),  a1);                            \
    a2 = fmaf((ss), (float)((ux >> 16) & 255), a2);                            \
    a3 = fmaf((ss), (float)(ux >> 24),         a3);                            \
    a4 = fmaf((ss), (float)(uy & 255),         a4);                            \
    a5 = fmaf((ss), (float)((uy >> 8) & 255),  a5);                            \
    a6 = fmaf((ss), (float)((uy >> 16) & 255), a6);                            \
    a7 = fmaf((ss), (float)(uy >> 24),         a7);                            \
} while (0)

// fused layer: branch-free unroll-8 int8 gather into LDS bf16 A-tile, MFMA vs global Wt.
// USRC=0: source rows are signed int8 (hn0); USRC=1: unsigned uint8 (post-ReLU).
template<int USRC>
__global__ __launch_bounds__(256) void k_layer(const uint2* __restrict__ hn2,
                                               const float* __restrict__ sc,
                                               const int* __restrict__ bucket,
                                               const int* __restrict__ deg_in,
                                               const int* __restrict__ deg_out,
                                               const unsigned short* __restrict__ Wt,
                                               const float* __restrict__ bias,
                                               void* __restrict__ OutP,
                                               float* __restrict__ scOut, int last) {
    __shared__ unsigned int at[64 * 68];   // 17.4 KB bf16 A-tile, row stride 68 words
    int tid = threadIdx.x;
    int m0 = blockIdx.x * 64;

    // phase 1: gather 64 node rows; 16 lanes/node (uint2 = 8 B int8 each), 4 passes
    int g = tid >> 4, l16p = tid & 15;
    #pragma unroll
    for (int pass = 0; pass < 4; ++pass) {
        int nl = pass * 16 + g;
        int n = m0 + nl;
        int cnt = deg_in[n];
        cnt = cnt < 64 ? cnt : 64;
        const int* brow = bucket + (size_t)n * 64;
        float a0 = 0, a1 = 0, a2 = 0, a3 = 0, a4 = 0, a5 = 0, a6 = 0, a7 = 0;
        for (int c = 0; c < cnt; c += 8) {
            int4 sA = *(const int4*)&brow[c];
            int4 sB = *(const int4*)&brow[c + 4];
            int lim = cnt - c;
            // branch-free: clamp indices to 0, fold validity into the dequant scale
            int i1 = lim > 1 ? sA.y : 0;
            int i2 = lim > 2 ? sA.z : 0;
            int i3 = lim > 3 ? sA.w : 0;
            int i4 = lim > 4 ? sB.x : 0;
            int i5 = lim > 5 ? sB.y : 0;
            int i6 = lim > 6 ? sB.z : 0;
            int i7 = lim > 7 ? sB.w : 0;
            uint2 v0 = hn2[(size_t)sA.x * 16 + l16p];
            uint2 v1 = hn2[(size_t)i1 * 16 + l16p];
            uint2 v2 = hn2[(size_t)i2 * 16 + l16p];
            uint2 v3 = hn2[(size_t)i3 * 16 + l16p];
            uint2 v4 = hn2[(size_t)i4 * 16 + l16p];
            uint2 v5 = hn2[(size_t)i5 * 16 + l16p];
            uint2 v6 = hn2[(size_t)i6 * 16 + l16p];
            uint2 v7 = hn2[(size_t)i7 * 16 + l16p];
            float s0 = sc[sA.x];
            float s1 = sc[i1]; s1 = lim > 1 ? s1 : 0.f;
            float s2 = sc[i2]; s2 = lim > 2 ? s2 : 0.f;
            float s3 = sc[i3]; s3 = lim > 3 ? s3 : 0.f;
            float s4 = sc[i4]; s4 = lim > 4 ? s4 : 0.f;
            float s5 = sc[i5]; s5 = lim > 5 ? s5 : 0.f;
            float s6 = sc[i6]; s6 = lim > 6 ? s6 : 0.f;
            float s7 = sc[i7]; s7 = lim > 7 ? s7 : 0.f;
            if (USRC) {
                DEQU8(v0, s0); DEQU8(v1, s1); DEQU8(v2, s2); DEQU8(v3, s3);
                DEQU8(v4, s4); DEQU8(v5, s5); DEQU8(v6, s6); DEQU8(v7, s7);
            } else {
                DEQS8(v0, s0); DEQS8(v1, s1); DEQS8(v2, s2); DEQS8(v3, s3);
                DEQS8(v4, s4); DEQS8(v5, s5); DEQS8(v6, s6); DEQS8(v7, s7);
            }
        }
        float nd = rsqrtf((float)(cnt > 1 ? cnt : 1));
        uint4 o;
        o.x = pack2(a0 * nd, a1 * nd); o.y = pack2(a2 * nd, a3 * nd);
        o.z = pack2(a4 * nd, a5 * nd); o.w = pack2(a6 * nd, a7 * nd);
        *(uint4*)&at[nl * 68 + l16p * 4] = o;
    }
    __syncthreads();

    // phase 2: MFMA 64x128; B-frags straight from global Wt (L2-hot, 32 KB)
    f32x4 acc[8];
    #pragma unroll
    for (int t = 0; t < 8; ++t) acc[t] = (f32x4){0.f, 0.f, 0.f, 0.f};
    int wave = tid >> 6, lane = tid & 63, quad = lane >> 4, l16 = lane & 15;
    int arow = (wave * 16 + l16) * 68 + quad * 4;
    #pragma unroll
    for (int ks = 0; ks < 4; ++ks) {
        bf16x8 af = *(const bf16x8*)&at[arow + ks * 16];
        #pragma unroll
        for (int t = 0; t < 8; ++t) {
            bf16x8 bf = *(const bf16x8*)(Wt + (t * 16 + l16) * 128 + ks * 32 + quad * 8);
            acc[t] = __builtin_amdgcn_mfma_f32_16x16x32_bf16(af, bf, acc[t], 0, 0, 0);
        }
    }

    int mb = wave * 16 + quad * 4;
    if (!last) {
        // bf16 LDS transpose (reuse A-tile) -> uint8 row-scaled coalesced write-out.
        // outputs are post-ReLU >= 0: unsigned, 254 levels over [0, amax].
        float nsr[4];
        #pragma unroll
        for (int r = 0; r < 4; ++r) {
            int dq = deg_out[m0 + mb + r];
            nsr[r] = rsqrtf((float)(dq > 1 ? dq : 1));
        }
        __syncthreads();   // all waves done reading A-tile
        unsigned short* atb = (unsigned short*)at;
        #pragma unroll
        for (int t = 0; t < 8; ++t) {
            float bv = bias[t * 16 + l16];
            #pragma unroll
            for (int r = 0; r < 4; ++r) {
                float v = acc[t][r] + bv;
                v = (v > 0.f ? v : 0.f) * nsr[r];
                atb[(mb + r) * 136 + t * 16 + l16] = (unsigned short)f2b(v);
            }
        }
        __syncthreads();
        int r = tid >> 2, cg = tid & 3;
        const unsigned int* sp = &at[r * 68 + cg * 16];
        float v[32]; float am = 0.f;
        #pragma unroll
        for (int j = 0; j < 16; ++j) {
            unsigned u = sp[j];
            float e = blo(u), o = bhi(u);
            v[2 * j] = e; v[2 * j + 1] = o;
            am = fmaxf(am, fmaxf(e, o));   // post-ReLU: values >= 0
        }
        am = fmaxf(am, __shfl_xor(am, 1));
        am = fmaxf(am, __shfl_xor(am, 2));
        float scl = am > 1e-30f ? 254.f / am : 0.f;
        if (cg == 0) scOut[m0 + r] = am * (1.f / 254.f);
        unsigned w[8];
        #pragma unroll
        for (int j = 0; j < 8; ++j)
            w[j] = packq((int)rintf(v[4 * j] * scl),     (int)rintf(v[4 * j + 1] * scl),
                         (int)rintf(v[4 * j + 2] * scl), (int)rintf(v[4 * j + 3] * scl));
        unsigned char* Out = (unsigned char*)OutP;
        uint4* op = (uint4*)(Out + (size_t)(m0 + r) * 128 + cg * 32);
        op[0] = (uint4){w[0], w[1], w[2], w[3]};
        op[1] = (uint4){w[4], w[5], w[6], w[7]};
    } else {
        // fp32 out: direct C-layout stores are full 64-B sectors (16 lanes x 4 B)
        float* Out = (float*)OutP;
        #pragma unroll
        for (int t = 0; t < 8; ++t) {
            float bv = bias[t * 16 + l16];
            #pragma unroll
            for (int r = 0; r < 4; ++r) {
                float v = acc[t][r] + bv;
                v = v > 0.f ? v : 0.f;
                Out[(size_t)(m0 + mb + r) * 128 + t * 16 + l16] = v;
            }
        }
    }
}

extern "C" void kernel_launch(void* const* d_in, const int* in_sizes, int n_in,
                              void* d_out, int out_size, void* d_ws, size_t ws_size,
                              hipStream_t stream) {
    const float* x  = (const float*)d_in[0];
    const int* src  = (const int*)d_in[1];
    const int* dst  = (const int*)d_in[2];
    const float* Wi = (const float*)d_in[3];
    const float* W1 = (const float*)d_in[4];
    const float* b1 = (const float*)d_in[5];
    const float* W2 = (const float*)d_in[6];
    const float* b2 = (const float*)d_in[7];
    const float* W3 = (const float*)d_in[8];
    const float* b3 = (const float*)d_in[9];

    char* ws = (char*)d_ws;
    int* deg_out   = (int*)(ws + OFF_DEG_OUT);
    int* cursor    = (int*)(ws + OFF_CURSOR);   // becomes deg_in
    unsigned short* Wt  = (unsigned short*)(ws + OFF_WT);
    unsigned short* Wti = (unsigned short*)(ws + OFF_WTI);
    int* bucket    = (int*)(ws + OFF_BUCKET);
    unsigned char* hnA = (unsigned char*)(ws + OFF_HN);
    float* scA     = (float*)(ws + OFF_SCA);
    float* scB     = (float*)(ws + OFF_SCB);
    unsigned char* hnB = (unsigned char*)d_out;   // int8 ping buffer inside d_out (16.8 MB)

    // k_wprep first: zeroes deg/cursor (replaces memset) + weight transposes
    k_wprep<<<256, 256, 0, stream>>>(W1, W2, W3, Wi, Wt, Wti, (uint4*)ws);
    k_fill<<<NE / 512, 256, 0, stream>>>(src, dst, deg_out, cursor, bucket);
    k_init<<<NN / 64, 256, 0, stream>>>(x, Wti, deg_out, hnA, scA);

    // ping-pong: L0 hnA(s8)->hnB(u8), L1 hnB(u8)->hnA(u8), L2 hnA(u8)->d_out(fp32)
    k_layer<0><<<NN / 64, 256, 0, stream>>>((const uint2*)hnA, scA, bucket, cursor, deg_out,
                                            Wt,         b1, (void*)hnB, scB, 0);
    k_layer<1><<<NN / 64, 256, 0, stream>>>((const uint2*)hnB, scB, bucket, cursor, deg_out,
                                            Wt + 16384, b2, (void*)hnA, scA, 0);
    k_layer<1><<<NN / 64, 256, 0, stream>>>((const uint2*)hnA, scA, bucket, cursor, deg_out,
                                            Wt + 32768, b3, d_out, nullptr, 1);
}

// Round 3
// 392.063 us; speedup vs baseline: 1.1377x; 1.0356x over previous
//
#include <hip/hip_runtime.h>

#define NN 131072   // total nodes (256 graphs x 512)
#define NE 1048576  // edges
// ws layout (bytes); total used = 0x3300000 (< 0x4200000 available)
#define OFF_DEG_OUT 0x000000   // int[NN]
#define OFF_CURSOR  0x080000   // int[NN] -> becomes deg_in
#define OFF_WT      0x100000   // bf16 3x[128][128] transposed layer weights (96 KB)
#define OFF_WTI     0x118000   // bf16 [128][96] transposed init weight, K-padded (24 KB)
#define OFF_BUCKET  0x200000   // int[NN][64] adjacency buckets (33.5 MB)
#define OFF_HN      0x2200000  // int8[NN][128] ping buffer A (16.8 MB)
#define OFF_SCA     0x3200000  // float[NN] per-row dequant scale for buffer A
#define OFF_SCB     0x3280000  // float[NN] per-row dequant scale for buffer B

typedef __attribute__((ext_vector_type(8))) short bf16x8;
typedef __attribute__((ext_vector_type(4))) float f32x4;

static __device__ __forceinline__ float blo(unsigned u){ return __uint_as_float(u << 16); }
static __device__ __forceinline__ float bhi(unsigned u){ return __uint_as_float(u & 0xffff0000u); }
static __device__ __forceinline__ unsigned f2b(float f){
    unsigned u = __float_as_uint(f);
    return (u + 0x7fffu + ((u >> 16) & 1u)) >> 16;   // round-to-nearest-even
}
static __device__ __forceinline__ unsigned pack2(float a, float b){
    return f2b(a) | (f2b(b) << 16);
}
static __device__ __forceinline__ unsigned packq(int q0, int q1, int q2, int q3){
    return (q0 & 255) | ((q1 & 255) << 8) | ((q2 & 255) << 16) | ((q3 & 255) << 24);
}

// weight transposes + zero deg/cursor (replaces the hipMemsetAsync dispatch).
// grid = 256 blocks = 65536 threads; each zeroes one uint4 of the 1 MB counter region.
__global__ __launch_bounds__(256) void k_wprep(const float* __restrict__ W1,
                                               const float* __restrict__ W2,
                                               const float* __restrict__ W3,
                                               const float* __restrict__ Wi,
                                               unsigned short* __restrict__ Wt,
                                               unsigned short* __restrict__ Wti,
                                               uint4* __restrict__ zdst) {
    int idx = blockIdx.x * 256 + threadIdx.x;
    zdst[idx] = (uint4){0u, 0u, 0u, 0u};
    if (idx < 49152) {
        int L = idx >> 14, rem = idx & 16383;
        int k = rem >> 7, n = rem & 127;
        const float* W = L == 0 ? W1 : (L == 1 ? W2 : W3);
        Wt[L * 16384 + n * 128 + k] = (unsigned short)f2b(W[k * 128 + n]);
    } else if (idx < 61440) {
        int rem = idx - 49152;
        int n = rem / 96, k = rem - n * 96;
        float v = (k < 74) ? Wi[k * 128 + n] : 0.f;
        Wti[n * 96 + k] = (unsigned short)f2b(v);
    }
}

// FUSED fill + init. k_fill is far-atomic-latency bound (VALUBusy 0.4%, HBM 13%):
// the machine is ~85% idle for ~93 us. k_init only depends on Wti (wprep), not on
// deg/cursor/bucket, once deg_out^-1/2 is moved into the dequant scale (k_scnorm).
// Role-interleave: even blocks = fill (2 edges/thread, atomics), odd = init (MFMA).
__global__ __launch_bounds__(256) void k_pre(const int* __restrict__ src,
                                             const int* __restrict__ dst,
                                             int* __restrict__ deg_out,
                                             int* __restrict__ cursor,
                                             int* __restrict__ bucket,
                                             const float* __restrict__ X,
                                             const unsigned short* __restrict__ Wti,
                                             unsigned char* __restrict__ hn,
                                             float* __restrict__ scInv) {
    __shared__ unsigned int xs[64 * 68];   // init role only; 17.4 KB
    int tid = threadIdx.x;

    if (!(blockIdx.x & 1)) {
        // ---- fill role: deg_out count + bucketed CSR build ----
        int base = ((blockIdx.x >> 1) * 256 + tid) * 2;
        int2 s2 = *(const int2*)&src[base];
        int2 d2 = *(const int2*)&dst[base];
        int p0 = atomicAdd(&cursor[d2.x], 1);
        int p1 = atomicAdd(&cursor[d2.y], 1);
        atomicAdd(&deg_out[s2.x], 1);
        atomicAdd(&deg_out[s2.y], 1);
        if (p0 < 64) bucket[(size_t)d2.x * 64 + p0] = s2.x;   // deg>=64 has P~1e-40
        if (p1 < 64) bucket[(size_t)d2.y * 64 + p1] = s2.y;
        return;
    }

    // ---- init role: hn0 = int8_rowscaled(x @ W_init) via MFMA (UNNORMALIZED;
    //      deg_out^-1/2 is folded into scInv by k_scnorm afterwards) ----
    int m0 = (blockIdx.x >> 1) * 64;

    for (int idx = tid; idx < 2368; idx += 256) {        // X: 64 rows x 37 float2, quantize
        int m = idx / 37, t = idx - m * 37;
        float2 v = *(const float2*)&X[(size_t)(m0 + m) * 74 + t * 2];
        xs[m * 68 + t] = pack2(v.x, v.y);
    }
    for (int idx = tid; idx < 64 * 11; idx += 256) {     // zero pad words 37..47 (K 74..95)
        int m = idx / 11, c = 37 + idx % 11;
        xs[m * 68 + c] = 0u;
    }
    __syncthreads();

    int wave = tid >> 6, lane = tid & 63, quad = lane >> 4, l16 = lane & 15;
    f32x4 acc[8];
    #pragma unroll
    for (int t = 0; t < 8; ++t) acc[t] = (f32x4){0.f, 0.f, 0.f, 0.f};
    int arow = (wave * 16 + l16) * 68 + quad * 4;
    #pragma unroll
    for (int ks = 0; ks < 3; ++ks) {
        bf16x8 af = *(const bf16x8*)&xs[arow + ks * 16];
        #pragma unroll
        for (int t = 0; t < 8; ++t) {
            bf16x8 bf = *(const bf16x8*)(Wti + (t * 16 + l16) * 96 + ks * 32 + quad * 8);
            acc[t] = __builtin_amdgcn_mfma_f32_16x16x32_bf16(af, bf, acc[t], 0, 0, 0);
        }
    }
    __syncthreads();   // done reading xs; reuse as bf16 epilogue tile [64][136 shorts]
    unsigned short* atb = (unsigned short*)xs;
    int mb = wave * 16 + quad * 4;
    #pragma unroll
    for (int t = 0; t < 8; ++t)
        #pragma unroll
        for (int r = 0; r < 4; ++r)
            atb[(mb + r) * 136 + t * 16 + l16] = (unsigned short)f2b(acc[t][r]);
    __syncthreads();
    {   // int8 write-out: 4 threads own a row; row-amax via shfl_xor; 32 B/thread coalesced
        int r = tid >> 2, cg = tid & 3;
        const unsigned int* sp = &xs[r * 68 + cg * 16];   // 16 words = 32 bf16 values
        float v[32]; float am = 0.f;
        #pragma unroll
        for (int j = 0; j < 16; ++j) {
            unsigned u = sp[j];
            float e = blo(u), o = bhi(u);
            v[2 * j] = e; v[2 * j + 1] = o;
            am = fmaxf(am, fmaxf(fabsf(e), fabsf(o)));
        }
        am = fmaxf(am, __shfl_xor(am, 1));
        am = fmaxf(am, __shfl_xor(am, 2));
        float scl = am > 1e-30f ? 127.f / am : 0.f;
        if (cg == 0) scInv[m0 + r] = am * (1.f / 127.f);
        unsigned w[8];
        #pragma unroll
        for (int j = 0; j < 8; ++j)
            w[j] = packq((int)rintf(v[4 * j] * scl),     (int)rintf(v[4 * j + 1] * scl),
                         (int)rintf(v[4 * j + 2] * scl), (int)rintf(v[4 * j + 3] * scl));
        uint4* op = (uint4*)(hn + (size_t)(m0 + r) * 128 + cg * 32);
        op[0] = (uint4){w[0], w[1], w[2], w[3]};
        op[1] = (uint4){w[4], w[5], w[6], w[7]};
    }
}

// compose deg_out^-1/2 into the per-row dequant scale (exact in fp32)
__global__ __launch_bounds__(256) void k_scnorm(float* __restrict__ sc,
                                                const int* __restrict__ deg) {
    int i = blockIdx.x * 256 + threadIdx.x;
    int d = deg[i];
    sc[i] *= rsqrtf((float)(d > 1 ? d : 1));
}

// dequant 8 bytes (one neighbor slice): signed int8 (hn0) — compiler emits bfe+cvt
#define DEQS8(vv, ss) do {                                                     \
    unsigned ux = (vv).x, uy = (vv).y;                                         \
    a0 = fmaf((ss), (float)(int)(signed char)(ux),       a0);                  \
    a1 = fmaf((ss), (float)(int)(signed char)(ux >> 8),  a1);                  \
    a2 = fmaf((ss), (float)(int)(signed char)(ux >> 16), a2);                  \
    a3 = fmaf((ss), (float)(int)(signed char)(ux >> 24), a3);                  \
    a4 = fmaf((ss), (float)(int)(signed char)(uy),       a4);                  \
    a5 = fmaf((ss), (float)(int)(signed char)(uy >> 8),  a5);                  \
    a6 = fmaf((ss), (float)(int)(signed char)(uy >> 16), a6);                  \
    a7 = fmaf((ss), (float)(int)(signed char)(uy >> 24), a7);                  \
} while (0)

// unsigned uint8 (post-ReLU hn1/hn2) — compiler emits v_cvt_f32_ubyte0..3
#define DEQU8(vv, ss) do {                                                     \
    unsigned ux = (vv).x, uy = (vv).y;                                         \
    a0 = fmaf((ss), (float)(ux & 255),         a0);                            \
    a1 = fmaf((ss), (float)((ux >> 8) & 255),  a1);                            \
    a2 = fmaf((ss), (float)((ux >> 16) & 255), a2);                            \
    a3 = fmaf((ss), (float)(ux >> 24),         a3);                            \
    a4 = fmaf((ss), (float)(uy & 255),         a4);                            \
    a5 = fmaf((ss), (float)((uy >> 8) & 255),  a5);                            \
    a6 = fmaf((ss), (float)((uy >> 16) & 255), a6);                            \
    a7 = fmaf((ss), (float)(uy >> 24),         a7);                            \
} while (0)

// fused layer: branch-free unroll-8 int8 gather into LDS bf16 A-tile, MFMA vs global Wt.
// USRC=0: source rows are signed int8 (hn0); USRC=1: unsigned uint8 (post-ReLU).
template<int USRC>
__global__ __launch_bounds__(256) void k_layer(const uint2* __restrict__ hn2,
                                               const float* __restrict__ sc,
                                               const int* __restrict__ bucket,
                                               const int* __restrict__ deg_in,
                                               const int* __restrict__ deg_out,
                                               const unsigned short* __restrict__ Wt,
                                               const float* __restrict__ bias,
                                               void* __restrict__ OutP,
                                               float* __restrict__ scOut, int last) {
    __shared__ unsigned int at[64 * 68];   // 17.4 KB bf16 A-tile, row stride 68 words
    int tid = threadIdx.x;
    int m0 = blockIdx.x * 64;

    // phase 1: gather 64 node rows; 16 lanes/node (uint2 = 8 B int8 each), 4 passes
    int g = tid >> 4, l16p = tid & 15;
    #pragma unroll
    for (int pass = 0; pass < 4; ++pass) {
        int nl = pass * 16 + g;
        int n = m0 + nl;
        int cnt = deg_in[n];
        cnt = cnt < 64 ? cnt : 64;
        const int* brow = bucket + (size_t)n * 64;
        float a0 = 0, a1 = 0, a2 = 0, a3 = 0, a4 = 0, a5 = 0, a6 = 0, a7 = 0;
        for (int c = 0; c < cnt; c += 8) {
            int4 sA = *(const int4*)&brow[c];
            int4 sB = *(const int4*)&brow[c + 4];
            int lim = cnt - c;
            // branch-free: clamp indices to 0, fold validity into the dequant scale
            int i1 = lim > 1 ? sA.y : 0;
            int i2 = lim > 2 ? sA.z : 0;
            int i3 = lim > 3 ? sA.w : 0;
            int i4 = lim > 4 ? sB.x : 0;
            int i5 = lim > 5 ? sB.y : 0;
            int i6 = lim > 6 ? sB.z : 0;
            int i7 = lim > 7 ? sB.w : 0;
            uint2 v0 = hn2[(size_t)sA.x * 16 + l16p];
            uint2 v1 = hn2[(size_t)i1 * 16 + l16p];
            uint2 v2 = hn2[(size_t)i2 * 16 + l16p];
            uint2 v3 = hn2[(size_t)i3 * 16 + l16p];
            uint2 v4 = hn2[(size_t)i4 * 16 + l16p];
            uint2 v5 = hn2[(size_t)i5 * 16 + l16p];
            uint2 v6 = hn2[(size_t)i6 * 16 + l16p];
            uint2 v7 = hn2[(size_t)i7 * 16 + l16p];
            float s0 = sc[sA.x];
            float s1 = sc[i1]; s1 = lim > 1 ? s1 : 0.f;
            float s2 = sc[i2]; s2 = lim > 2 ? s2 : 0.f;
            float s3 = sc[i3]; s3 = lim > 3 ? s3 : 0.f;
            float s4 = sc[i4]; s4 = lim > 4 ? s4 : 0.f;
            float s5 = sc[i5]; s5 = lim > 5 ? s5 : 0.f;
            float s6 = sc[i6]; s6 = lim > 6 ? s6 : 0.f;
            float s7 = sc[i7]; s7 = lim > 7 ? s7 : 0.f;
            if (USRC) {
                DEQU8(v0, s0); DEQU8(v1, s1); DEQU8(v2, s2); DEQU8(v3, s3);
                DEQU8(v4, s4); DEQU8(v5, s5); DEQU8(v6, s6); DEQU8(v7, s7);
            } else {
                DEQS8(v0, s0); DEQS8(v1, s1); DEQS8(v2, s2); DEQS8(v3, s3);
                DEQS8(v4, s4); DEQS8(v5, s5); DEQS8(v6, s6); DEQS8(v7, s7);
            }
        }
        float nd = rsqrtf((float)(cnt > 1 ? cnt : 1));
        uint4 o;
        o.x = pack2(a0 * nd, a1 * nd); o.y = pack2(a2 * nd, a3 * nd);
        o.z = pack2(a4 * nd, a5 * nd); o.w = pack2(a6 * nd, a7 * nd);
        *(uint4*)&at[nl * 68 + l16p * 4] = o;
    }
    __syncthreads();

    // phase 2: MFMA 64x128; B-frags straight from global Wt (L2-hot, 32 KB)
    f32x4 acc[8];
    #pragma unroll
    for (int t = 0; t < 8; ++t) acc[t] = (f32x4){0.f, 0.f, 0.f, 0.f};
    int wave = tid >> 6, lane = tid & 63, quad = lane >> 4, l16 = lane & 15;
    int arow = (wave * 16 + l16) * 68 + quad * 4;
    #pragma unroll
    for (int ks = 0; ks < 4; ++ks) {
        bf16x8 af = *(const bf16x8*)&at[arow + ks * 16];
        #pragma unroll
        for (int t = 0; t < 8; ++t) {
            bf16x8 bf = *(const bf16x8*)(Wt + (t * 16 + l16) * 128 + ks * 32 + quad * 8);
            acc[t] = __builtin_amdgcn_mfma_f32_16x16x32_bf16(af, bf, acc[t], 0, 0, 0);
        }
    }

    int mb = wave * 16 + quad * 4;
    if (!last) {
        // bf16 LDS transpose (reuse A-tile) -> uint8 row-scaled coalesced write-out.
        // outputs are post-ReLU >= 0: unsigned, 254 levels over [0, amax].
        float nsr[4];
        #pragma unroll
        for (int r = 0; r < 4; ++r) {
            int dq = deg_out[m0 + mb + r];
            nsr[r] = rsqrtf((float)(dq > 1 ? dq : 1));
        }
        __syncthreads();   // all waves done reading A-tile
        unsigned short* atb = (unsigned short*)at;
        #pragma unroll
        for (int t = 0; t < 8; ++t) {
            float bv = bias[t * 16 + l16];
            #pragma unroll
            for (int r = 0; r < 4; ++r) {
                float v = acc[t][r] + bv;
                v = (v > 0.f ? v : 0.f) * nsr[r];
                atb[(mb + r) * 136 + t * 16 + l16] = (unsigned short)f2b(v);
            }
        }
        __syncthreads();
        int r = tid >> 2, cg = tid & 3;
        const unsigned int* sp = &at[r * 68 + cg * 16];
        float v[32]; float am = 0.f;
        #pragma unroll
        for (int j = 0; j < 16; ++j) {
            unsigned u = sp[j];
            float e = blo(u), o = bhi(u);
            v[2 * j] = e; v[2 * j + 1] = o;
            am = fmaxf(am, fmaxf(e, o));   // post-ReLU: values >= 0
        }
        am = fmaxf(am, __shfl_xor(am, 1));
        am = fmaxf(am, __shfl_xor(am, 2));
        float scl = am > 1e-30f ? 254.f / am : 0.f;
        if (cg == 0) scOut[m0 + r] = am * (1.f / 254.f);
        unsigned w[8];
        #pragma unroll
        for (int j = 0; j < 8; ++j)
            w[j] = packq((int)rintf(v[4 * j] * scl),     (int)rintf(v[4 * j + 1] * scl),
                         (int)rintf(v[4 * j + 2] * scl), (int)rintf(v[4 * j + 3] * scl));
        unsigned char* Out = (unsigned char*)OutP;
        uint4* op = (uint4*)(Out + (size_t)(m0 + r) * 128 + cg * 32);
        op[0] = (uint4){w[0], w[1], w[2], w[3]};
        op[1] = (uint4){w[4], w[5], w[6], w[7]};
    } else {
        // fp32 out: direct C-layout stores are full 64-B sectors (16 lanes x 4 B)
        float* Out = (float*)OutP;
        #pragma unroll
        for (int t = 0; t < 8; ++t) {
            float bv = bias[t * 16 + l16];
            #pragma unroll
            for (int r = 0; r < 4; ++r) {
                float v = acc[t][r] + bv;
                v = v > 0.f ? v : 0.f;
                Out[(size_t)(m0 + mb + r) * 128 + t * 16 + l16] = v;
            }
        }
    }
}

extern "C" void kernel_launch(void* const* d_in, const int* in_sizes, int n_in,
                              void* d_out, int out_size, void* d_ws, size_t ws_size,
                              hipStream_t stream) {
    const float* x  = (const float*)d_in[0];
    const int* src  = (const int*)d_in[1];
    const int* dst  = (const int*)d_in[2];
    const float* Wi = (const float*)d_in[3];
    const float* W1 = (const float*)d_in[4];
    const float* b1 = (const float*)d_in[5];
    const float* W2 = (const float*)d_in[6];
    const float* b2 = (const float*)d_in[7];
    const float* W3 = (const float*)d_in[8];
    const float* b3 = (const float*)d_in[9];

    char* ws = (char*)d_ws;
    int* deg_out   = (int*)(ws + OFF_DEG_OUT);
    int* cursor    = (int*)(ws + OFF_CURSOR);   // becomes deg_in
    unsigned short* Wt  = (unsigned short*)(ws + OFF_WT);
    unsigned short* Wti = (unsigned short*)(ws + OFF_WTI);
    int* bucket    = (int*)(ws + OFF_BUCKET);
    unsigned char* hnA = (unsigned char*)(ws + OFF_HN);
    float* scA     = (float*)(ws + OFF_SCA);
    float* scB     = (float*)(ws + OFF_SCB);
    unsigned char* hnB = (unsigned char*)d_out;   // int8 ping buffer inside d_out (16.8 MB)

    // k_wprep: zeroes deg/cursor + weight transposes (Wti ready before k_pre)
    k_wprep<<<256, 256, 0, stream>>>(W1, W2, W3, Wi, Wt, Wti, (uint4*)ws);
    // fused fill+init: atomics-latency-bound fill blocks interleaved with MFMA init blocks
    k_pre<<<4096, 256, 0, stream>>>(src, dst, deg_out, cursor, bucket, x, Wti, hnA, scA);
    // fold deg_out^-1/2 into hn0's dequant scale (exact)
    k_scnorm<<<NN / 256, 256, 0, stream>>>(scA, deg_out);

    // ping-pong: L0 hnA(s8)->hnB(u8), L1 hnB(u8)->hnA(u8), L2 hnA(u8)->d_out(fp32)
    k_layer<0><<<NN / 64, 256, 0, stream>>>((const uint2*)hnA, scA, bucket, cursor, deg_out,
                                            Wt,         b1, (void*)hnB, scB, 0);
    k_layer<1><<<NN / 64, 256, 0, stream>>>((const uint2*)hnB, scB, bucket, cursor, deg_out,
                                            Wt + 16384, b2, (void*)hnA, scA, 0);
    k_layer<1><<<NN / 64, 256, 0, stream>>>((const uint2*)hnA, scA, bucket, cursor, deg_out,
                                            Wt + 32768, b3, d_out, nullptr, 1);
}